// Round 3
// baseline (16460.248 us; speedup 1.0000x reference)
//
#include <hip/hip_runtime.h>
#include <hip/hip_bf16.h>

// Problem constants
#define T_STEPS 512
#define BATCH   64
#define IDIM    1024
#define HDIM    1024
#define GDIM    4096   // 4*HDIM
#define UPB     16     // hidden units per recurrence block
#define LSTM_BLOCKS 64 // HDIM / UPB

typedef __attribute__((ext_vector_type(8))) short short8;
typedef __attribute__((ext_vector_type(8))) unsigned short ushort8;
typedef __attribute__((ext_vector_type(4))) float f32x4;

static __device__ __forceinline__ unsigned short f2bf(float f) {
    union { float f; unsigned u; } x; x.f = f;
    unsigned r = x.u + 0x7fffu + ((x.u >> 16) & 1u);  // round-to-nearest-even
    return (unsigned short)(r >> 16);
}

// 16B of h (8 bf16) via 4 agent-scope relaxed atomic loads: global_load_dword
// sc0 sc1 -> bypasses L1/L2, reads the MALL coherence point. No cache
// maintenance instructions needed anywhere.
static __device__ __forceinline__ short8 h_load16(const unsigned* __restrict__ p) {
    union { unsigned u[4]; short8 s; } h;
#pragma unroll
    for (int i = 0; i < 4; ++i)
        h.u[i] = __hip_atomic_load(p + i, __ATOMIC_RELAXED, __HIP_MEMORY_SCOPE_AGENT);
    return h.s;
}

// ---------------------------------------------------------------------------
// Kernel 0: convert h0 (fp32 [B,H]) -> bf16 buffer 0 (normal stores; flushed
// to memory at kernel end, so sc1 reads in k_lstm see them).
// ---------------------------------------------------------------------------
__global__ void k_h0_to_bf16(const float* __restrict__ h0,
                             unsigned short* __restrict__ hbuf0) {
    int i = blockIdx.x * 256 + threadIdx.x;   // grid covers exactly B*H = 65536
    hbuf0[i] = f2bf(h0[i]);
}

// ---------------------------------------------------------------------------
// Kernel 1: gx = input @ W_x^T + b_x + b_h   (unchanged from round 1/2)
// ---------------------------------------------------------------------------
__global__ __launch_bounds__(256) void k_gx_gemm(
        const float* __restrict__ X, const float* __restrict__ Wx,
        const float* __restrict__ bx, const float* __restrict__ bh,
        float* __restrict__ gx) {
    __shared__ unsigned short As[128][40];
    __shared__ unsigned short Bs[128][40];

    const int bid  = blockIdx.x;
    const int nt   = bid & 31;     // 32 N tiles
    const int mt   = bid >> 5;     // 256 M tiles
    const int tid  = threadIdx.x;
    const int lane = tid & 63;
    const int w    = tid >> 6;
    const int wm   = (w >> 1) * 64;
    const int wn   = (w & 1) * 64;
    const int lmod = lane & 15;
    const int lk8  = (lane >> 4) * 8;

    f32x4 acc[4][4] = {};

    const int srow = tid >> 1;
    const int scol = (tid & 1) * 16;
    const float* Abase = X  + (size_t)(mt * 128 + srow) * 1024 + scol;
    const float* Bbase = Wx + (size_t)(nt * 128 + srow) * 1024 + scol;

    for (int k0 = 0; k0 < 1024; k0 += 32) {
        const float4* a4 = reinterpret_cast<const float4*>(Abase + k0);
        const float4* b4 = reinterpret_cast<const float4*>(Bbase + k0);
        ushort8 pa[2], pb[2];
#pragma unroll
        for (int h = 0; h < 2; ++h) {
            float4 v0 = a4[h * 2], v1 = a4[h * 2 + 1];
            ushort8 t;
            t[0]=f2bf(v0.x); t[1]=f2bf(v0.y); t[2]=f2bf(v0.z); t[3]=f2bf(v0.w);
            t[4]=f2bf(v1.x); t[5]=f2bf(v1.y); t[6]=f2bf(v1.z); t[7]=f2bf(v1.w);
            pa[h] = t;
            float4 u0 = b4[h * 2], u1 = b4[h * 2 + 1];
            ushort8 s;
            s[0]=f2bf(u0.x); s[1]=f2bf(u0.y); s[2]=f2bf(u0.z); s[3]=f2bf(u0.w);
            s[4]=f2bf(u1.x); s[5]=f2bf(u1.y); s[6]=f2bf(u1.z); s[7]=f2bf(u1.w);
            pb[h] = s;
        }
        __syncthreads();
        *reinterpret_cast<ushort8*>(&As[srow][scol])     = pa[0];
        *reinterpret_cast<ushort8*>(&As[srow][scol + 8]) = pa[1];
        *reinterpret_cast<ushort8*>(&Bs[srow][scol])     = pb[0];
        *reinterpret_cast<ushort8*>(&Bs[srow][scol + 8]) = pb[1];
        __syncthreads();

        short8 af[4], bf_[4];
#pragma unroll
        for (int i = 0; i < 4; ++i)
            af[i] = *reinterpret_cast<const short8*>(&As[wm + i * 16 + lmod][lk8]);
#pragma unroll
        for (int i = 0; i < 4; ++i)
            bf_[i] = *reinterpret_cast<const short8*>(&Bs[wn + i * 16 + lmod][lk8]);
#pragma unroll
        for (int i = 0; i < 4; ++i)
#pragma unroll
            for (int j = 0; j < 4; ++j)
                acc[i][j] = __builtin_amdgcn_mfma_f32_16x16x32_bf16(
                                af[i], bf_[j], acc[i][j], 0, 0, 0);
    }

#pragma unroll
    for (int j = 0; j < 4; ++j) {
        int n = nt * 128 + wn + j * 16 + lmod;
        float bb = bx[n] + bh[n];
#pragma unroll
        for (int i = 0; i < 4; ++i) {
            int mbase = mt * 128 + wm + i * 16 + (lane >> 4) * 4;
#pragma unroll
            for (int r = 0; r < 4; ++r)
                gx[(size_t)(mbase + r) * GDIM + n] = acc[i][j][r] + bb;
        }
    }
}

// ---------------------------------------------------------------------------
// Kernel 2: persistent LSTM recurrence, fence-free.
// 64 blocks x 256 threads. Block b owns hidden units [b*16, b*16+16).
// All cross-block traffic (h double-buffer + flags) moves through the MALL
// via agent-scope relaxed atomics (sc0 sc1 write-through stores / bypass
// loads). No __threadfence -> no buffer_wbl2/buffer_inv; gx stays L2-cached.
// ---------------------------------------------------------------------------
__global__ __launch_bounds__(256, 1) void k_lstm(
        const float* __restrict__ gx, const float* __restrict__ Wh,
        const float* __restrict__ cinit, float* __restrict__ out,
        unsigned* __restrict__ hbuf32, unsigned* __restrict__ bar) {
    __shared__ __align__(16) unsigned short Wl[64][1032]; // 129 KB, pad->2-way
    __shared__ __align__(16) float gs[64][68];            // 17 KB
    __shared__ __align__(16) unsigned short hs[64][16];   // 2 KB h staging

    const int b    = blockIdx.x;     // 64
    const int tid  = threadIdx.x;    // 256
    const int lane = tid & 63;
    const int w    = tid >> 6;       // 0..3

    // ---- W_h slice -> LDS bf16. Local col n <-> W_h row (n>>4)*H + b*16 + (n&15)
    {
        const int n    = tid >> 2;            // 0..63
        const int cseg = (tid & 3) * 256;     // K segment
        const int wrow = (n >> 4) * HDIM + b * UPB + (n & 15);
        const float* src = Wh + (size_t)wrow * HDIM + cseg;
#pragma unroll 4
        for (int j = 0; j < 256; j += 4) {
            float4 v = *reinterpret_cast<const float4*>(src + j);
            Wl[n][cseg + j + 0] = f2bf(v.x);
            Wl[n][cseg + j + 1] = f2bf(v.y);
            Wl[n][cseg + j + 2] = f2bf(v.z);
            Wl[n][cseg + j + 3] = f2bf(v.w);
        }
    }

    // ---- per-thread gate ownership: unit u, batch rows mg*4..mg*4+3
    const int u   = tid & 15;
    const int mg  = tid >> 4;        // 0..15
    const int col = b * UPB + u;     // global hidden index

    float c_reg[4];
#pragma unroll
    for (int r = 0; r < 4; ++r)
        c_reg[r] = cinit[(size_t)(mg * 4 + r) * HDIM + col];

    // gx for t=0
    float gxv[4][4];
#pragma unroll
    for (int r = 0; r < 4; ++r)
#pragma unroll
        for (int g = 0; g < 4; ++g)
            gxv[r][g] = gx[(size_t)(mg * 4 + r) * GDIM + g * HDIM + col];

    __syncthreads();

    // ---- wave tile: 2x2 waves, each 32x32 output, full K
    const int wm  = (w & 1) * 32;
    const int wn  = (w >> 1) * 32;
    const int l15 = lane & 15;
    const int lk  = (lane >> 4) * 8;
    const unsigned short* wp0 = &Wl[wn + l15][lk];
    const unsigned short* wp1 = &Wl[wn + 16 + l15][lk];

    // packed h-store mapping: thread i -> rows {i>>3, (i>>3)+32}, unit-pair i&7
    const int srow0 = tid >> 3;          // 0..31
    const int su2   = tid & 7;           // unit pair within block slice

    for (int t = 0; t < T_STEPS; ++t) {
        const unsigned* h32in = hbuf32 + (size_t)(t & 1) * (BATCH * HDIM / 2);
        const unsigned* hq0 = h32in + (size_t)(wm + l15) * (HDIM / 2) + (lk >> 1);
        const unsigned* hq1 = hq0 + (size_t)16 * (HDIM / 2);

        f32x4 acc00 = {}, acc01 = {}, acc10 = {}, acc11 = {};
#pragma unroll
        for (int ks = 0; ks < 32; ++ks) {
            short8 a0 = h_load16(hq0 + ks * 16);
            short8 a1 = h_load16(hq1 + ks * 16);
            short8 b0 = *reinterpret_cast<const short8*>(wp0 + ks * 32);
            short8 b1 = *reinterpret_cast<const short8*>(wp1 + ks * 32);
            acc00 = __builtin_amdgcn_mfma_f32_16x16x32_bf16(a0, b0, acc00, 0, 0, 0);
            acc01 = __builtin_amdgcn_mfma_f32_16x16x32_bf16(a0, b1, acc01, 0, 0, 0);
            acc10 = __builtin_amdgcn_mfma_f32_16x16x32_bf16(a1, b0, acc10, 0, 0, 0);
            acc11 = __builtin_amdgcn_mfma_f32_16x16x32_bf16(a1, b1, acc11, 0, 0, 0);
        }
        {
            const int gr = (lane >> 4) * 4;
#pragma unroll
            for (int r = 0; r < 4; ++r) {
                gs[wm + gr + r][wn + l15]           = acc00[r];
                gs[wm + gr + r][wn + 16 + l15]      = acc01[r];
                gs[wm + 16 + gr + r][wn + l15]      = acc10[r];
                gs[wm + 16 + gr + r][wn + 16 + l15] = acc11[r];
            }
        }
        __syncthreads();

        // ---- gates + state update (all 256 threads, 4 batch rows each)
        float hv[4];
#pragma unroll
        for (int r = 0; r < 4; ++r) {
            const int m = mg * 4 + r;
            float xi = gxv[r][0] + gs[m][u];
            float xf = gxv[r][1] + gs[m][16 + u];
            float xo = gxv[r][2] + gs[m][32 + u];
            float xn = gxv[r][3] + gs[m][48 + u];
            float ig = 1.f / (1.f + expf(-xi));
            float fg = 1.f / (1.f + expf(-xf));
            float og = 1.f / (1.f + expf(-xo));
            float ng = tanhf(xn);
            c_reg[r] = fg * c_reg[r] + ig * ng;
            float h = og * tanhf(c_reg[r]);
            hv[r] = h;
            out[((size_t)t * BATCH + m) * HDIM + col] = h;
            hs[m][u] = f2bf(h);
        }

        if (t == T_STEPS - 1) {
            size_t fin = (size_t)T_STEPS * BATCH * HDIM;
#pragma unroll
            for (int r = 0; r < 4; ++r) {
                const int m = mg * 4 + r;
                out[fin + (size_t)m * HDIM + col] = hv[r];                     // h_fin
                out[fin + (size_t)BATCH * HDIM + (size_t)m * HDIM + col] = c_reg[r]; // c_fin
            }
            break;   // no barrier needed after the last step
        }

        __syncthreads();   // hs complete

        // ---- packed h store -> MALL (write-through agent atomics, coalesced)
        {
            unsigned* hout = hbuf32 + (size_t)((t + 1) & 1) * (BATCH * HDIM / 2);
#pragma unroll
            for (int rr = 0; rr < 2; ++rr) {
                const int row = srow0 + rr * 32;
                unsigned lo = hs[row][su2 * 2];
                unsigned hi = hs[row][su2 * 2 + 1];
                unsigned val = lo | (hi << 16);
                __hip_atomic_store(hout + (size_t)row * (HDIM / 2) + b * 8 + su2,
                                   val, __ATOMIC_RELAXED, __HIP_MEMORY_SCOPE_AGENT);
            }
        }

        // implicit s_waitcnt vmcnt(0) before s_barrier drains the h stores of
        // ALL waves in this block before the flag goes up
        __syncthreads();
        if (tid == 0)
            __hip_atomic_store(&bar[b * 32], (unsigned)(t + 1),
                               __ATOMIC_RELAXED, __HIP_MEMORY_SCOPE_AGENT);

        // ---- prefetch gx[t+1] into registers (in flight during the poll)
        {
            const float* gp = gx + (size_t)(t + 1) * BATCH * GDIM;
#pragma unroll
            for (int r = 0; r < 4; ++r)
#pragma unroll
                for (int g = 0; g < 4; ++g)
                    gxv[r][g] = gp[(size_t)(mg * 4 + r) * GDIM + g * HDIM + col];
        }

        // ---- wave 0 polls all 64 flags (one bypass load + ballot per round)
        if (w == 0) {
            const unsigned tgt = (unsigned)(t + 1);
            while (true) {
                unsigned v = __hip_atomic_load(&bar[lane * 32],
                                               __ATOMIC_RELAXED,
                                               __HIP_MEMORY_SCOPE_AGENT);
                if (__all((int)(v >= tgt))) break;
                __builtin_amdgcn_s_sleep(1);
            }
        }
        __syncthreads();
    }
}

// ---------------------------------------------------------------------------
extern "C" void kernel_launch(void* const* d_in, const int* in_sizes, int n_in,
                              void* d_out, int out_size, void* d_ws, size_t ws_size,
                              hipStream_t stream) {
    const float* X  = (const float*)d_in[0];
    const float* h0 = (const float*)d_in[1];
    const float* c0 = (const float*)d_in[2];
    const float* Wx = (const float*)d_in[3];
    const float* Wh = (const float*)d_in[4];
    const float* bx = (const float*)d_in[5];
    const float* bh = (const float*)d_in[6];
    float* out = (float*)d_out;

    char* ws = (char*)d_ws;
    float* gx = (float*)ws;                                   // 512 MB fp32
    size_t gx_bytes = (size_t)T_STEPS * BATCH * GDIM * 4;
    unsigned short* hbuf = (unsigned short*)(ws + gx_bytes);  // 256 KB bf16 x2
    size_t hbuf_bytes = (size_t)2 * BATCH * HDIM * 2;
    unsigned* bar = (unsigned*)(ws + gx_bytes + hbuf_bytes);  // 64 flags, 128B apart

    hipMemsetAsync(bar, 0, LSTM_BLOCKS * 32 * sizeof(unsigned), stream);
    k_h0_to_bf16<<<dim3(256), dim3(256), 0, stream>>>(h0, hbuf);
    k_gx_gemm<<<dim3(8192), dim3(256), 0, stream>>>(X, Wx, bx, bh, gx);
    k_lstm<<<dim3(LSTM_BLOCKS), dim3(256), 0, stream>>>(gx, Wh, c0, out,
                                                        (unsigned*)hbuf, bar);
}

// Round 4
// 4871.476 us; speedup vs baseline: 3.3789x; 3.3789x over previous
//
#include <hip/hip_runtime.h>
#include <hip/hip_bf16.h>

// Problem constants
#define T_STEPS 512
#define BATCH   64
#define IDIM    1024
#define HDIM    1024
#define GDIM    4096   // 4*HDIM
#define UPB     16     // hidden units per recurrence block
#define LSTM_BLOCKS 64 // HDIM / UPB
#define WSTRIDE 1032   // Wl row stride in shorts (2064B: 16B-aligned, 2-way banks)

typedef __attribute__((ext_vector_type(8))) short short8;
typedef __attribute__((ext_vector_type(8))) unsigned short ushort8;
typedef __attribute__((ext_vector_type(4))) float f32x4;

static __device__ __forceinline__ unsigned short f2bf(float f) {
    union { float f; unsigned u; } x; x.f = f;
    unsigned r = x.u + 0x7fffu + ((x.u >> 16) & 1u);  // round-to-nearest-even
    return (unsigned short)(r >> 16);
}

// 16B coherent-bypass load (skips L1/L2, reads MALL coherence point).
template<int OFF>
static __device__ __forceinline__ short8 ldg16(const unsigned short* p) {
    short8 d;
    asm volatile("global_load_dwordx4 %0, %1, off offset:%2 sc0 sc1"
                 : "=v"(d) : "v"(p), "n"(OFF));
    return d;
}

// counted vmcnt wait + scheduler fence (keeps MFMAs from hoisting above it)
#define VMW(n) do { asm volatile("s_waitcnt vmcnt(" #n ")"); \
                    __builtin_amdgcn_sched_barrier(0); } while (0)

// ---------------------------------------------------------------------------
// Kernel 0: convert h0 (fp32 [B,H]) -> bf16 buffer 0
// ---------------------------------------------------------------------------
__global__ void k_h0_to_bf16(const float* __restrict__ h0,
                             unsigned short* __restrict__ hbuf0) {
    int i = blockIdx.x * 256 + threadIdx.x;   // grid covers exactly B*H = 65536
    hbuf0[i] = f2bf(h0[i]);
}

// ---------------------------------------------------------------------------
// Kernel 1: gx = input @ W_x^T + b_x + b_h   (unchanged; passed rounds 1-3)
// ---------------------------------------------------------------------------
__global__ __launch_bounds__(256) void k_gx_gemm(
        const float* __restrict__ X, const float* __restrict__ Wx,
        const float* __restrict__ bx, const float* __restrict__ bh,
        float* __restrict__ gx) {
    __shared__ unsigned short As[128][40];
    __shared__ unsigned short Bs[128][40];

    const int bid  = blockIdx.x;
    const int nt   = bid & 31;     // 32 N tiles
    const int mt   = bid >> 5;     // 256 M tiles
    const int tid  = threadIdx.x;
    const int lane = tid & 63;
    const int w    = tid >> 6;
    const int wm   = (w >> 1) * 64;
    const int wn   = (w & 1) * 64;
    const int lmod = lane & 15;
    const int lk8  = (lane >> 4) * 8;

    f32x4 acc[4][4] = {};

    const int srow = tid >> 1;
    const int scol = (tid & 1) * 16;
    const float* Abase = X  + (size_t)(mt * 128 + srow) * 1024 + scol;
    const float* Bbase = Wx + (size_t)(nt * 128 + srow) * 1024 + scol;

    for (int k0 = 0; k0 < 1024; k0 += 32) {
        const float4* a4 = reinterpret_cast<const float4*>(Abase + k0);
        const float4* b4 = reinterpret_cast<const float4*>(Bbase + k0);
        ushort8 pa[2], pb[2];
#pragma unroll
        for (int h = 0; h < 2; ++h) {
            float4 v0 = a4[h * 2], v1 = a4[h * 2 + 1];
            ushort8 t;
            t[0]=f2bf(v0.x); t[1]=f2bf(v0.y); t[2]=f2bf(v0.z); t[3]=f2bf(v0.w);
            t[4]=f2bf(v1.x); t[5]=f2bf(v1.y); t[6]=f2bf(v1.z); t[7]=f2bf(v1.w);
            pa[h] = t;
            float4 u0 = b4[h * 2], u1 = b4[h * 2 + 1];
            ushort8 s;
            s[0]=f2bf(u0.x); s[1]=f2bf(u0.y); s[2]=f2bf(u0.z); s[3]=f2bf(u0.w);
            s[4]=f2bf(u1.x); s[5]=f2bf(u1.y); s[6]=f2bf(u1.z); s[7]=f2bf(u1.w);
            pb[h] = s;
        }
        __syncthreads();
        *reinterpret_cast<ushort8*>(&As[srow][scol])     = pa[0];
        *reinterpret_cast<ushort8*>(&As[srow][scol + 8]) = pa[1];
        *reinterpret_cast<ushort8*>(&Bs[srow][scol])     = pb[0];
        *reinterpret_cast<ushort8*>(&Bs[srow][scol + 8]) = pb[1];
        __syncthreads();

        short8 af[4], bf_[4];
#pragma unroll
        for (int i = 0; i < 4; ++i)
            af[i] = *reinterpret_cast<const short8*>(&As[wm + i * 16 + lmod][lk8]);
#pragma unroll
        for (int i = 0; i < 4; ++i)
            bf_[i] = *reinterpret_cast<const short8*>(&Bs[wn + i * 16 + lmod][lk8]);
#pragma unroll
        for (int i = 0; i < 4; ++i)
#pragma unroll
            for (int j = 0; j < 4; ++j)
                acc[i][j] = __builtin_amdgcn_mfma_f32_16x16x32_bf16(
                                af[i], bf_[j], acc[i][j], 0, 0, 0);
    }

#pragma unroll
    for (int j = 0; j < 4; ++j) {
        int n = nt * 128 + wn + j * 16 + lmod;
        float bb = bx[n] + bh[n];
#pragma unroll
        for (int i = 0; i < 4; ++i) {
            int mbase = mt * 128 + wm + i * 16 + (lane >> 4) * 4;
#pragma unroll
            for (int r = 0; r < 4; ++r)
                gx[(size_t)(mbase + r) * GDIM + n] = acc[i][j][r] + bb;
        }
    }
}

// ---------------------------------------------------------------------------
// Kernel 2: persistent LSTM recurrence, fence-free, wide-bypass h loads.
// 64 blocks x 256 threads. Block b owns hidden units [b*16, b*16+16).
// Wave w computes batch rows [w*16, w*16+16) x all 64 gate-cols: per K-step
// ONE 16B bypass A-load (h) + 4 LDS B-reads + 4 MFMA. All 32 A-loads issued
// up-front; consumption gated by counted vmcnt (24/16/8/0).
// Per-wave independent flag polling (no block-internal sync on the barrier).
// ---------------------------------------------------------------------------
__global__ __launch_bounds__(256, 1) void k_lstm(
        const float* __restrict__ gx, const float* __restrict__ Wh,
        const float* __restrict__ cinit, float* __restrict__ out,
        unsigned short* __restrict__ hbuf, unsigned* __restrict__ bar) {
    __shared__ __align__(16) unsigned short Wl[64][WSTRIDE]; // 129 KB
    __shared__ __align__(16) float gs[64][68];               // 17 KB
    __shared__ __align__(16) unsigned short hs[64][16];      // 2 KB

    const int b    = blockIdx.x;     // 64
    const int tid  = threadIdx.x;    // 256
    const int lane = tid & 63;
    const int w    = tid >> 6;       // 0..3

    // ---- W_h slice -> LDS bf16. Local row n: gate = n>>4, unit = n&15.
    {
        const int n    = tid >> 2;            // 0..63
        const int cseg = (tid & 3) * 256;     // K segment
        const int wrow = (n >> 4) * HDIM + b * UPB + (n & 15);
        const float* src = Wh + (size_t)wrow * HDIM + cseg;
#pragma unroll 4
        for (int j = 0; j < 256; j += 4) {
            float4 v = *reinterpret_cast<const float4*>(src + j);
            Wl[n][cseg + j + 0] = f2bf(v.x);
            Wl[n][cseg + j + 1] = f2bf(v.y);
            Wl[n][cseg + j + 2] = f2bf(v.z);
            Wl[n][cseg + j + 3] = f2bf(v.w);
        }
    }

    // ---- per-thread gate ownership: unit u, batch rows mg*4..mg*4+3
    const int u   = tid & 15;
    const int mg  = tid >> 4;        // 0..15
    const int col = b * UPB + u;     // global hidden index

    float c_reg[4];
#pragma unroll
    for (int r = 0; r < 4; ++r)
        c_reg[r] = cinit[(size_t)(mg * 4 + r) * HDIM + col];

    // gx for t=0
    float gxv[4][4];
#pragma unroll
    for (int r = 0; r < 4; ++r)
#pragma unroll
        for (int g = 0; g < 4; ++g)
            gxv[r][g] = gx[(size_t)(mg * 4 + r) * GDIM + g * HDIM + col];

    __syncthreads();

    const int l15  = lane & 15;
    const int lk   = (lane >> 4) * 8;    // K element offset within 32-elem step
    const int wm16 = w * 16;             // this wave's batch-row base

    // packed h-store mapping: thread i -> row i>>2, u32 pair (i&3)*2
    const int prow = tid >> 2;           // 0..63
    const int pj   = tid & 3;

    for (int t = 0; t < T_STEPS; ++t) {
        // ---- per-wave poll: all 64 flags >= t  (h(t) visible at MALL)
        {
            while (true) {
                unsigned v = __hip_atomic_load(&bar[lane * 32],
                                               __ATOMIC_RELAXED,
                                               __HIP_MEMORY_SCOPE_AGENT);
                if (__all((int)(v >= (unsigned)t))) break;
                __builtin_amdgcn_s_sleep(4);
            }
        }
        asm volatile("" ::: "memory");   // fence: keep bypass loads below poll

        // ---- issue all 32 A-loads (16 rows x 1024 K, this wave's rows)
        const unsigned short* hb = hbuf + (size_t)(t & 1) * (BATCH * HDIM)
                                 + (size_t)(wm16 + l15) * HDIM + lk;
        short8 st[32];
#define ISS(i) st[i] = ldg16<(i) * 64>(hb)
        ISS(0);  ISS(1);  ISS(2);  ISS(3);  ISS(4);  ISS(5);  ISS(6);  ISS(7);
        ISS(8);  ISS(9);  ISS(10); ISS(11); ISS(12); ISS(13); ISS(14); ISS(15);
        ISS(16); ISS(17); ISS(18); ISS(19); ISS(20); ISS(21); ISS(22); ISS(23);
        ISS(24); ISS(25); ISS(26); ISS(27); ISS(28); ISS(29); ISS(30); ISS(31);
#undef ISS

        f32x4 acc0 = {}, acc1 = {}, acc2 = {}, acc3 = {};
#define KS(i) do { \
        short8 b0 = *reinterpret_cast<const short8*>(&Wl[     l15][lk + (i) * 32]); \
        short8 b1 = *reinterpret_cast<const short8*>(&Wl[16 + l15][lk + (i) * 32]); \
        short8 b2 = *reinterpret_cast<const short8*>(&Wl[32 + l15][lk + (i) * 32]); \
        short8 b3 = *reinterpret_cast<const short8*>(&Wl[48 + l15][lk + (i) * 32]); \
        acc0 = __builtin_amdgcn_mfma_f32_16x16x32_bf16(st[i], b0, acc0, 0, 0, 0); \
        acc1 = __builtin_amdgcn_mfma_f32_16x16x32_bf16(st[i], b1, acc1, 0, 0, 0); \
        acc2 = __builtin_amdgcn_mfma_f32_16x16x32_bf16(st[i], b2, acc2, 0, 0, 0); \
        acc3 = __builtin_amdgcn_mfma_f32_16x16x32_bf16(st[i], b3, acc3, 0, 0, 0); \
    } while (0)
        VMW(24);
        KS(0);  KS(1);  KS(2);  KS(3);  KS(4);  KS(5);  KS(6);  KS(7);
        VMW(16);
        KS(8);  KS(9);  KS(10); KS(11); KS(12); KS(13); KS(14); KS(15);
        VMW(8);
        KS(16); KS(17); KS(18); KS(19); KS(20); KS(21); KS(22); KS(23);
        VMW(0);
        KS(24); KS(25); KS(26); KS(27); KS(28); KS(29); KS(30); KS(31);
#undef KS

        // ---- accs -> gs  (rows wm16 + (lane>>4)*4 + r, cols g*16 + l15)
        {
            const int gr = wm16 + (lane >> 4) * 4;
#pragma unroll
            for (int r = 0; r < 4; ++r) {
                gs[gr + r][     l15] = acc0[r];
                gs[gr + r][16 + l15] = acc1[r];
                gs[gr + r][32 + l15] = acc2[r];
                gs[gr + r][48 + l15] = acc3[r];
            }
        }
        __syncthreads();

        // ---- gates + state update (all 256 threads, 4 batch rows each)
        float hv[4];
#pragma unroll
        for (int r = 0; r < 4; ++r) {
            const int m = mg * 4 + r;
            float xi = gxv[r][0] + gs[m][u];
            float xf = gxv[r][1] + gs[m][16 + u];
            float xo = gxv[r][2] + gs[m][32 + u];
            float xn = gxv[r][3] + gs[m][48 + u];
            float ig = 1.f / (1.f + expf(-xi));
            float fg = 1.f / (1.f + expf(-xf));
            float og = 1.f / (1.f + expf(-xo));
            float ng = tanhf(xn);
            c_reg[r] = fg * c_reg[r] + ig * ng;
            float h = og * tanhf(c_reg[r]);
            hv[r] = h;
            out[((size_t)t * BATCH + m) * HDIM + col] = h;
            hs[m][u] = f2bf(h);
        }

        if (t == T_STEPS - 1) {
            size_t fin = (size_t)T_STEPS * BATCH * HDIM;
#pragma unroll
            for (int r = 0; r < 4; ++r) {
                const int m = mg * 4 + r;
                out[fin + (size_t)m * HDIM + col] = hv[r];                           // h_fin
                out[fin + (size_t)BATCH * HDIM + (size_t)m * HDIM + col] = c_reg[r]; // c_fin
            }
            break;
        }

        __syncthreads();   // hs complete

        // ---- packed h store -> MALL (write-through agent atomics, coalesced)
        {
            unsigned* hout = (unsigned*)hbuf
                           + (size_t)((t + 1) & 1) * (BATCH * HDIM / 2);
            unsigned v0 = (unsigned)hs[prow][pj * 4 + 0]
                        | ((unsigned)hs[prow][pj * 4 + 1] << 16);
            unsigned v1 = (unsigned)hs[prow][pj * 4 + 2]
                        | ((unsigned)hs[prow][pj * 4 + 3] << 16);
            unsigned* dst = hout + (size_t)prow * (HDIM / 2) + b * 8 + pj * 2;
            __hip_atomic_store(dst,     v0, __ATOMIC_RELAXED, __HIP_MEMORY_SCOPE_AGENT);
            __hip_atomic_store(dst + 1, v1, __ATOMIC_RELAXED, __HIP_MEMORY_SCOPE_AGENT);
        }

        // __syncthreads = s_waitcnt vmcnt(0)+barrier: all h stores of this
        // block are at the coherence point before the flag goes up.
        __syncthreads();
        if (tid == 0)
            __hip_atomic_store(&bar[b * 32], (unsigned)(t + 1),
                               __ATOMIC_RELAXED, __HIP_MEMORY_SCOPE_AGENT);

        // ---- prefetch gx[t+1] into registers (in flight during next poll)
        {
            const float* gp = gx + (size_t)(t + 1) * BATCH * GDIM;
#pragma unroll
            for (int r = 0; r < 4; ++r)
#pragma unroll
                for (int g = 0; g < 4; ++g)
                    gxv[r][g] = gp[(size_t)(mg * 4 + r) * GDIM + g * HDIM + col];
        }
    }
}

// ---------------------------------------------------------------------------
extern "C" void kernel_launch(void* const* d_in, const int* in_sizes, int n_in,
                              void* d_out, int out_size, void* d_ws, size_t ws_size,
                              hipStream_t stream) {
    const float* X  = (const float*)d_in[0];
    const float* h0 = (const float*)d_in[1];
    const float* c0 = (const float*)d_in[2];
    const float* Wx = (const float*)d_in[3];
    const float* Wh = (const float*)d_in[4];
    const float* bx = (const float*)d_in[5];
    const float* bh = (const float*)d_in[6];
    float* out = (float*)d_out;

    char* ws = (char*)d_ws;
    float* gx = (float*)ws;                                   // 512 MB fp32
    size_t gx_bytes = (size_t)T_STEPS * BATCH * GDIM * 4;
    unsigned short* hbuf = (unsigned short*)(ws + gx_bytes);  // 256 KB bf16 x2
    size_t hbuf_bytes = (size_t)2 * BATCH * HDIM * 2;
    unsigned* bar = (unsigned*)(ws + gx_bytes + hbuf_bytes);  // 64 flags, 128B apart

    hipMemsetAsync(bar, 0, LSTM_BLOCKS * 32 * sizeof(unsigned), stream);
    k_h0_to_bf16<<<dim3(256), dim3(256), 0, stream>>>(h0, hbuf);
    k_gx_gemm<<<dim3(8192), dim3(256), 0, stream>>>(X, Wx, bx, bh, gx);
    k_lstm<<<dim3(LSTM_BLOCKS), dim3(256), 0, stream>>>(gx, Wh, c0, out, hbuf, bar);
}

// Round 5
// 3746.394 us; speedup vs baseline: 4.3936x; 1.3003x over previous
//
#include <hip/hip_runtime.h>
#include <hip/hip_bf16.h>

// Problem constants
#define T_STEPS 512
#define BATCH   64
#define IDIM    1024
#define HDIM    1024
#define GDIM    4096   // 4*HDIM
#define UPB     16     // hidden units per recurrence block
#define LSTM_BLOCKS 64 // HDIM / UPB

typedef __attribute__((ext_vector_type(8))) short short8;
typedef __attribute__((ext_vector_type(8))) unsigned short ushort8;
typedef __attribute__((ext_vector_type(4))) float f32x4;

static __device__ __forceinline__ unsigned short f2bf(float f) {
    union { float f; unsigned u; } x; x.f = f;
    unsigned r = x.u + 0x7fffu + ((x.u >> 16) & 1u);  // round-to-nearest-even
    return (unsigned short)(r >> 16);
}

static __device__ __forceinline__ short8 pack8(const float* p) {
    float4 v0 = *reinterpret_cast<const float4*>(p);
    float4 v1 = *reinterpret_cast<const float4*>(p + 4);
    short8 t;
    t[0]=(short)f2bf(v0.x); t[1]=(short)f2bf(v0.y);
    t[2]=(short)f2bf(v0.z); t[3]=(short)f2bf(v0.w);
    t[4]=(short)f2bf(v1.x); t[5]=(short)f2bf(v1.y);
    t[6]=(short)f2bf(v1.z); t[7]=(short)f2bf(v1.w);
    return t;
}

// 16B coherent-bypass load/store (skip L1/L2; MALL coherence point).
static __device__ __forceinline__ short8 ldg16(const unsigned short* p) {
    short8 d;
    asm volatile("global_load_dwordx4 %0, %1, off sc0 sc1" : "=v"(d) : "v"(p));
    return d;
}
static __device__ __forceinline__ void stg16(unsigned short* p, ushort8 v) {
    asm volatile("global_store_dwordx4 %0, %1, off sc0 sc1"
                 :: "v"(p), "v"(v) : "memory");
}

// counted vmcnt wait + scheduler fence (keeps MFMAs from hoisting above it)
#define VMW(n) do { asm volatile("s_waitcnt vmcnt(" #n ")"); \
                    __builtin_amdgcn_sched_barrier(0); } while (0)

// ---------------------------------------------------------------------------
// Kernel 0: h0 (fp32 [B,H]) -> swizzled bf16 buffer 0.
// Layout: 16B chunk index (Rtile*32 + s)*64 + lane holds
//   h[Rtile*16 + (lane&15)][s*32 + (lane>>4)*8 .. +8)
// so a consumer A-fragment load is 64 lanes x contiguous 16B.
// ---------------------------------------------------------------------------
__global__ void k_h0_swz(const float* __restrict__ h0,
                         unsigned short* __restrict__ hbuf0) {
    int i = blockIdx.x * 256 + threadIdx.x;   // 8192 threads: 64 rows x 128 chunks
    int m  = i >> 7;
    int hh = i & 127;                         // u = hh*8
    const float* src = h0 + (size_t)m * HDIM + hh * 8;
    float4 a = *reinterpret_cast<const float4*>(src);
    float4 c = *reinterpret_cast<const float4*>(src + 4);
    ushort8 v;
    v[0]=f2bf(a.x); v[1]=f2bf(a.y); v[2]=f2bf(a.z); v[3]=f2bf(a.w);
    v[4]=f2bf(c.x); v[5]=f2bf(c.y); v[6]=f2bf(c.z); v[7]=f2bf(c.w);
    size_t dst16 = ((size_t)(m >> 4) * 32 + (hh >> 2)) * 64 + (m & 15) + 16 * (hh & 3);
    *reinterpret_cast<ushort8*>(hbuf0 + dst16 * 8) = v;  // kernel-end flush -> MALL
}

// ---------------------------------------------------------------------------
// Kernel 1: gx = input @ W_x^T + b_x + b_h   (unchanged; passed rounds 1-4)
// ---------------------------------------------------------------------------
__global__ __launch_bounds__(256) void k_gx_gemm(
        const float* __restrict__ X, const float* __restrict__ Wx,
        const float* __restrict__ bx, const float* __restrict__ bh,
        float* __restrict__ gx) {
    __shared__ unsigned short As[128][40];
    __shared__ unsigned short Bs[128][40];

    const int bid  = blockIdx.x;
    const int nt   = bid & 31;     // 32 N tiles
    const int mt   = bid >> 5;     // 256 M tiles
    const int tid  = threadIdx.x;
    const int lane = tid & 63;
    const int w    = tid >> 6;
    const int wm   = (w >> 1) * 64;
    const int wn   = (w & 1) * 64;
    const int lmod = lane & 15;
    const int lk8  = (lane >> 4) * 8;

    f32x4 acc[4][4] = {};

    const int srow = tid >> 1;
    const int scol = (tid & 1) * 16;
    const float* Abase = X  + (size_t)(mt * 128 + srow) * 1024 + scol;
    const float* Bbase = Wx + (size_t)(nt * 128 + srow) * 1024 + scol;

    for (int k0 = 0; k0 < 1024; k0 += 32) {
        const float4* a4 = reinterpret_cast<const float4*>(Abase + k0);
        const float4* b4 = reinterpret_cast<const float4*>(Bbase + k0);
        ushort8 pa[2], pb[2];
#pragma unroll
        for (int h = 0; h < 2; ++h) {
            float4 v0 = a4[h * 2], v1 = a4[h * 2 + 1];
            ushort8 t;
            t[0]=f2bf(v0.x); t[1]=f2bf(v0.y); t[2]=f2bf(v0.z); t[3]=f2bf(v0.w);
            t[4]=f2bf(v1.x); t[5]=f2bf(v1.y); t[6]=f2bf(v1.z); t[7]=f2bf(v1.w);
            pa[h] = t;
            float4 u0 = b4[h * 2], u1 = b4[h * 2 + 1];
            ushort8 s;
            s[0]=f2bf(u0.x); s[1]=f2bf(u0.y); s[2]=f2bf(u0.z); s[3]=f2bf(u0.w);
            s[4]=f2bf(u1.x); s[5]=f2bf(u1.y); s[6]=f2bf(u1.z); s[7]=f2bf(u1.w);
            pb[h] = s;
        }
        __syncthreads();
        *reinterpret_cast<ushort8*>(&As[srow][scol])     = pa[0];
        *reinterpret_cast<ushort8*>(&As[srow][scol + 8]) = pa[1];
        *reinterpret_cast<ushort8*>(&Bs[srow][scol])     = pb[0];
        *reinterpret_cast<ushort8*>(&Bs[srow][scol + 8]) = pb[1];
        __syncthreads();

        short8 af[4], bf_[4];
#pragma unroll
        for (int i = 0; i < 4; ++i)
            af[i] = *reinterpret_cast<const short8*>(&As[wm + i * 16 + lmod][lk8]);
#pragma unroll
        for (int i = 0; i < 4; ++i)
            bf_[i] = *reinterpret_cast<const short8*>(&Bs[wn + i * 16 + lmod][lk8]);
#pragma unroll
        for (int i = 0; i < 4; ++i)
#pragma unroll
            for (int j = 0; j < 4; ++j)
                acc[i][j] = __builtin_amdgcn_mfma_f32_16x16x32_bf16(
                                af[i], bf_[j], acc[i][j], 0, 0, 0);
    }

#pragma unroll
    for (int j = 0; j < 4; ++j) {
        int n = nt * 128 + wn + j * 16 + lmod;
        float bb = bx[n] + bh[n];
#pragma unroll
        for (int i = 0; i < 4; ++i) {
            int mbase = mt * 128 + wm + i * 16 + (lane >> 4) * 4;
#pragma unroll
            for (int r = 0; r < 4; ++r)
                gx[(size_t)(mbase + r) * GDIM + n] = acc[i][j][r] + bb;
        }
    }
}

// ---------------------------------------------------------------------------
// Kernel 2: persistent LSTM recurrence.
// 64 blocks x 256 threads (4 waves). Block b owns hidden units [b*16, b*16+16)
// = 64 gate-cols. W_h slice lives in REGISTERS (short8 breg[64] = 256 VGPR per
// wave; quadrant tiling 32x32/wave) -> zero LDS B-traffic. h double-buffer in
// ws in the swizzled layout so every A-fragment is ONE contiguous 1024B
// bypass load. Flag-array barrier; wave 0 polls.
// ---------------------------------------------------------------------------
__global__ __launch_bounds__(256, 1) void k_lstm(
        const float* __restrict__ gx, const float* __restrict__ Wh,
        const float* __restrict__ cinit, float* __restrict__ out,
        unsigned short* __restrict__ hbuf, unsigned* __restrict__ bar) {
    __shared__ __align__(16) float gs[64][68];            // 17 KB
    __shared__ __align__(16) unsigned short hs[64][16];   // 2 KB

    const int b    = blockIdx.x;     // 64
    const int tid  = threadIdx.x;    // 256
    const int lane = tid & 63;
    const int w    = tid >> 6;       // 0..3
    const int qr   = w >> 1;         // quadrant row (batch half)
    const int qc   = w & 1;          // quadrant col (gate-col half)
    const int l15  = lane & 15;
    const int lk8  = (lane >> 4) * 8;

    // ---- W_h quadrant -> registers. breg[cg*32+s]: cols qc*32+cg*16+(l&15),
    //      k = s*32 + (lane>>4)*8 .. +8   (one-time, cached loads)
    short8 breg[64];
    {
        const float* wb0 = Wh + (size_t)((qc * 2 + 0) * HDIM + b * UPB + l15) * HDIM + lk8;
        const float* wb1 = Wh + (size_t)((qc * 2 + 1) * HDIM + b * UPB + l15) * HDIM + lk8;
#pragma unroll
        for (int s = 0; s < 32; ++s) {
            breg[s]      = pack8(wb0 + s * 32);
            breg[32 + s] = pack8(wb1 + s * 32);
        }
    }

    // ---- per-thread gate ownership: unit u, batch rows mg*4..mg*4+3
    const int u   = tid & 15;
    const int mg  = tid >> 4;        // 0..15
    const int col = b * UPB + u;     // global hidden index

    float c_reg[4];
#pragma unroll
    for (int r = 0; r < 4; ++r)
        c_reg[r] = cinit[(size_t)(mg * 4 + r) * HDIM + col];

    // gx for t=0
    float gxv[4][4];
#pragma unroll
    for (int r = 0; r < 4; ++r)
#pragma unroll
        for (int g = 0; g < 4; ++g)
            gxv[r][g] = gx[(size_t)(mg * 4 + r) * GDIM + g * HDIM + col];

    __syncthreads();

    for (int t = 0; t < T_STEPS; ++t) {
        // ---- wave 0 polls all 64 flags >= t; others wait at the barrier
        if (w == 0) {
            while (true) {
                unsigned v = __hip_atomic_load(&bar[lane * 32],
                                               __ATOMIC_RELAXED,
                                               __HIP_MEMORY_SCOPE_AGENT);
                if (__all((int)(v >= (unsigned)t))) break;
                __builtin_amdgcn_s_sleep(2);
            }
        }
        __syncthreads();
        asm volatile("" ::: "memory");   // keep bypass loads below the poll

        // ---- A-fragment stream: frag(rt,s) = 1024B contiguous at
        //      hb + ((qr*2+rt)*32 + s)*1024B, lane offset lane*16B
        const unsigned short* hA = hbuf + (size_t)(t & 1) * (BATCH * HDIM)
                                 + ((size_t)(qr * 2) * 32 * 64 + lane) * 8;
        short8 ast[16];
#define ISS1(slot, rt, s) ast[slot] = ldg16(hA + (rt) * 16384 + (s) * 512)
#define ISSG(g) do { \
        ISS1(((g)&1)*8+0, 0, 4*(g)+0); ISS1(((g)&1)*8+1, 1, 4*(g)+0); \
        ISS1(((g)&1)*8+2, 0, 4*(g)+1); ISS1(((g)&1)*8+3, 1, 4*(g)+1); \
        ISS1(((g)&1)*8+4, 0, 4*(g)+2); ISS1(((g)&1)*8+5, 1, 4*(g)+2); \
        ISS1(((g)&1)*8+6, 0, 4*(g)+3); ISS1(((g)&1)*8+7, 1, 4*(g)+3); \
    } while (0)
#define CONS1(g, j) do { \
        acc00 = __builtin_amdgcn_mfma_f32_16x16x32_bf16(ast[((g)&1)*8+(j)*2+0], breg[4*(g)+(j)],        acc00, 0, 0, 0); \
        acc01 = __builtin_amdgcn_mfma_f32_16x16x32_bf16(ast[((g)&1)*8+(j)*2+0], breg[32 + 4*(g)+(j)],   acc01, 0, 0, 0); \
        acc10 = __builtin_amdgcn_mfma_f32_16x16x32_bf16(ast[((g)&1)*8+(j)*2+1], breg[4*(g)+(j)],        acc10, 0, 0, 0); \
        acc11 = __builtin_amdgcn_mfma_f32_16x16x32_bf16(ast[((g)&1)*8+(j)*2+1], breg[32 + 4*(g)+(j)],   acc11, 0, 0, 0); \
    } while (0)
#define CONSG(g) do { CONS1(g,0); CONS1(g,1); CONS1(g,2); CONS1(g,3); } while (0)

        f32x4 acc00 = {}, acc01 = {}, acc10 = {}, acc11 = {};
        ISSG(0); ISSG(1);
        VMW(8); CONSG(0); ISSG(2);
        VMW(8); CONSG(1); ISSG(3);
        VMW(8); CONSG(2); ISSG(4);
        VMW(8); CONSG(3); ISSG(5);
        VMW(8); CONSG(4); ISSG(6);
        VMW(8); CONSG(5); ISSG(7);
        VMW(8); CONSG(6);
        VMW(0); CONSG(7);
#undef ISS1
#undef ISSG
#undef CONS1
#undef CONSG

        // ---- accs -> gs  (quadrant qr,qc)
        {
            const int gr = qr * 32 + (lane >> 4) * 4;
            const int c0 = qc * 32 + l15;
#pragma unroll
            for (int r = 0; r < 4; ++r) {
                gs[gr + r][c0]           = acc00[r];
                gs[gr + r][c0 + 16]      = acc01[r];
                gs[gr + 16 + r][c0]      = acc10[r];
                gs[gr + 16 + r][c0 + 16] = acc11[r];
            }
        }
        __syncthreads();

        // ---- gates + state update (all 256 threads, 4 batch rows each)
        float hv[4];
#pragma unroll
        for (int r = 0; r < 4; ++r) {
            const int m = mg * 4 + r;
            float xi = gxv[r][0] + gs[m][u];
            float xf = gxv[r][1] + gs[m][16 + u];
            float xo = gxv[r][2] + gs[m][32 + u];
            float xn = gxv[r][3] + gs[m][48 + u];
            float ig = 1.f / (1.f + expf(-xi));
            float fg = 1.f / (1.f + expf(-xf));
            float og = 1.f / (1.f + expf(-xo));
            float ng = tanhf(xn);
            c_reg[r] = fg * c_reg[r] + ig * ng;
            float h = og * tanhf(c_reg[r]);
            hv[r] = h;
            hs[m][u] = f2bf(h);
        }

        if (t == T_STEPS - 1) {
            size_t fin = (size_t)T_STEPS * BATCH * HDIM;
#pragma unroll
            for (int r = 0; r < 4; ++r) {
                const int m = mg * 4 + r;
                out[((size_t)t * BATCH + m) * HDIM + col] = hv[r];
                out[fin + (size_t)m * HDIM + col] = hv[r];                           // h_fin
                out[fin + (size_t)BATCH * HDIM + (size_t)m * HDIM + col] = c_reg[r]; // c_fin
            }
            break;
        }

        __syncthreads();   // hs complete

        // ---- packed swizzled h store -> MALL (128 threads x 16B, 256B runs)
        if (tid < 128) {
            const int m  = tid >> 1;
            const int hh = tid & 1;
            ushort8 v = *reinterpret_cast<const ushort8*>(&hs[m][hh * 8]);
            size_t dst16 = ((size_t)(m >> 4) * 32 + (b >> 1)) * 64 + (m & 15)
                         + 16 * (((b & 1) << 1) | hh);
            stg16(hbuf + (size_t)((t + 1) & 1) * (BATCH * HDIM) + dst16 * 8, v);
        }
        VMW(0);            // asm stores drained to the coherence point
        __syncthreads();
        if (tid == 0)
            __hip_atomic_store(&bar[b * 32], (unsigned)(t + 1),
                               __ATOMIC_RELAXED, __HIP_MEMORY_SCOPE_AGENT);

        // ---- out stores for step t + gx prefetch (hidden under next poll)
#pragma unroll
        for (int r = 0; r < 4; ++r)
            out[((size_t)t * BATCH + mg * 4 + r) * HDIM + col] = hv[r];
        {
            const float* gp = gx + (size_t)(t + 1) * BATCH * GDIM;
#pragma unroll
            for (int r = 0; r < 4; ++r)
#pragma unroll
                for (int g = 0; g < 4; ++g)
                    gxv[r][g] = gp[(size_t)(mg * 4 + r) * GDIM + g * HDIM + col];
        }
    }
}

// ---------------------------------------------------------------------------
extern "C" void kernel_launch(void* const* d_in, const int* in_sizes, int n_in,
                              void* d_out, int out_size, void* d_ws, size_t ws_size,
                              hipStream_t stream) {
    const float* X  = (const float*)d_in[0];
    const float* h0 = (const float*)d_in[1];
    const float* c0 = (const float*)d_in[2];
    const float* Wx = (const float*)d_in[3];
    const float* Wh = (const float*)d_in[4];
    const float* bx = (const float*)d_in[5];
    const float* bh = (const float*)d_in[6];
    float* out = (float*)d_out;

    char* ws = (char*)d_ws;
    float* gx = (float*)ws;                                   // 512 MB fp32
    size_t gx_bytes = (size_t)T_STEPS * BATCH * GDIM * 4;
    unsigned short* hbuf = (unsigned short*)(ws + gx_bytes);  // 2 x 128 KB swizzled bf16
    size_t hbuf_bytes = (size_t)2 * BATCH * HDIM * 2;
    unsigned* bar = (unsigned*)(ws + gx_bytes + hbuf_bytes);  // 64 flags, 128B apart

    hipMemsetAsync(bar, 0, LSTM_BLOCKS * 32 * sizeof(unsigned), stream);
    k_h0_swz<<<dim3(32), dim3(256), 0, stream>>>(h0, hbuf);
    k_gx_gemm<<<dim3(8192), dim3(256), 0, stream>>>(X, Wx, bx, bh, gx);
    k_lstm<<<dim3(LSTM_BLOCKS), dim3(256), 0, stream>>>(gx, Wh, c0, out, hbuf, bar);
}

// Round 6
// 3062.661 us; speedup vs baseline: 5.3745x; 1.2232x over previous
//
#include <hip/hip_runtime.h>
#include <hip/hip_bf16.h>

// Problem constants
#define T_STEPS 512
#define BATCH   64
#define IDIM    1024
#define HDIM    1024
#define GDIM    4096   // 4*HDIM
#define UPB     16     // hidden units per recurrence block
#define LSTM_BLOCKS 64 // HDIM / UPB

typedef __attribute__((ext_vector_type(8))) short short8;
typedef __attribute__((ext_vector_type(8))) unsigned short ushort8;
typedef __attribute__((ext_vector_type(4))) float f32x4;

static __device__ __forceinline__ unsigned short f2bf(float f) {
    union { float f; unsigned u; } x; x.f = f;
    unsigned r = x.u + 0x7fffu + ((x.u >> 16) & 1u);  // round-to-nearest-even
    return (unsigned short)(r >> 16);
}

static __device__ __forceinline__ short8 pack8(const float* p) {
    float4 v0 = *reinterpret_cast<const float4*>(p);
    float4 v1 = *reinterpret_cast<const float4*>(p + 4);
    short8 t;
    t[0]=(short)f2bf(v0.x); t[1]=(short)f2bf(v0.y);
    t[2]=(short)f2bf(v0.z); t[3]=(short)f2bf(v0.w);
    t[4]=(short)f2bf(v1.x); t[5]=(short)f2bf(v1.y);
    t[6]=(short)f2bf(v1.z); t[7]=(short)f2bf(v1.w);
    return t;
}

// 16B coherent-bypass load/store (skip L1/L2; MALL coherence point).
static __device__ __forceinline__ short8 ldg16(const unsigned short* p) {
    short8 d;
    asm volatile("global_load_dwordx4 %0, %1, off sc0 sc1" : "=v"(d) : "v"(p));
    return d;
}
static __device__ __forceinline__ void stg16(unsigned short* p, ushort8 v) {
    asm volatile("global_store_dwordx4 %0, %1, off sc0 sc1"
                 :: "v"(p), "v"(v) : "memory");
}

// counted vmcnt wait + scheduler fence (keeps MFMAs from hoisting above it)
#define VMW(n) do { asm volatile("s_waitcnt vmcnt(" #n ")"); \
                    __builtin_amdgcn_sched_barrier(0); } while (0)

// fast activations: v_exp_f32 computes 2^x; v_rcp_f32 ~1ULP
static __device__ __forceinline__ float fexp2(float x) {
    float r; asm("v_exp_f32 %0, %1" : "=v"(r) : "v"(x)); return r;
}
static __device__ __forceinline__ float frcp(float x) {
    float r; asm("v_rcp_f32 %0, %1" : "=v"(r) : "v"(x)); return r;
}
static __device__ __forceinline__ float fsigmoid(float x) {
    return frcp(1.f + fexp2(-1.4426950408889634f * x));
}
static __device__ __forceinline__ float ftanh(float x) {
    return 2.f * frcp(1.f + fexp2(-2.8853900817779268f * x)) - 1.f;
}

// ---------------------------------------------------------------------------
// Kernel 0: h0 (fp32 [B,H]) -> swizzled bf16 buffer 0.
// 16B chunk index (Rtile*32 + s)*64 + lane holds
//   h[Rtile*16 + (lane&15)][s*32 + (lane>>4)*8 .. +8)
// ---------------------------------------------------------------------------
__global__ void k_h0_swz(const float* __restrict__ h0,
                         unsigned short* __restrict__ hbuf0) {
    int i = blockIdx.x * 256 + threadIdx.x;   // 8192 threads: 64 rows x 128 chunks
    int m  = i >> 7;
    int hh = i & 127;                         // u = hh*8
    const float* src = h0 + (size_t)m * HDIM + hh * 8;
    float4 a = *reinterpret_cast<const float4*>(src);
    float4 c = *reinterpret_cast<const float4*>(src + 4);
    ushort8 v;
    v[0]=f2bf(a.x); v[1]=f2bf(a.y); v[2]=f2bf(a.z); v[3]=f2bf(a.w);
    v[4]=f2bf(c.x); v[5]=f2bf(c.y); v[6]=f2bf(c.z); v[7]=f2bf(c.w);
    size_t dst16 = ((size_t)(m >> 4) * 32 + (hh >> 2)) * 64 + (m & 15) + 16 * (hh & 3);
    *reinterpret_cast<ushort8*>(hbuf0 + dst16 * 8) = v;  // kernel-end flush -> MALL
}

// ---------------------------------------------------------------------------
// Kernel 1: gx = input @ W_x^T + b_x + b_h   (unchanged; passed rounds 1-5)
// ---------------------------------------------------------------------------
__global__ __launch_bounds__(256) void k_gx_gemm(
        const float* __restrict__ X, const float* __restrict__ Wx,
        const float* __restrict__ bx, const float* __restrict__ bh,
        float* __restrict__ gx) {
    __shared__ unsigned short As[128][40];
    __shared__ unsigned short Bs[128][40];

    const int bid  = blockIdx.x;
    const int nt   = bid & 31;     // 32 N tiles
    const int mt   = bid >> 5;     // 256 M tiles
    const int tid  = threadIdx.x;
    const int lane = tid & 63;
    const int w    = tid >> 6;
    const int wm   = (w >> 1) * 64;
    const int wn   = (w & 1) * 64;
    const int lmod = lane & 15;
    const int lk8  = (lane >> 4) * 8;

    f32x4 acc[4][4] = {};

    const int srow = tid >> 1;
    const int scol = (tid & 1) * 16;
    const float* Abase = X  + (size_t)(mt * 128 + srow) * 1024 + scol;
    const float* Bbase = Wx + (size_t)(nt * 128 + srow) * 1024 + scol;

    for (int k0 = 0; k0 < 1024; k0 += 32) {
        const float4* a4 = reinterpret_cast<const float4*>(Abase + k0);
        const float4* b4 = reinterpret_cast<const float4*>(Bbase + k0);
        ushort8 pa[2], pb[2];
#pragma unroll
        for (int h = 0; h < 2; ++h) {
            float4 v0 = a4[h * 2], v1 = a4[h * 2 + 1];
            ushort8 t;
            t[0]=f2bf(v0.x); t[1]=f2bf(v0.y); t[2]=f2bf(v0.z); t[3]=f2bf(v0.w);
            t[4]=f2bf(v1.x); t[5]=f2bf(v1.y); t[6]=f2bf(v1.z); t[7]=f2bf(v1.w);
            pa[h] = t;
            float4 u0 = b4[h * 2], u1 = b4[h * 2 + 1];
            ushort8 s;
            s[0]=f2bf(u0.x); s[1]=f2bf(u0.y); s[2]=f2bf(u0.z); s[3]=f2bf(u0.w);
            s[4]=f2bf(u1.x); s[5]=f2bf(u1.y); s[6]=f2bf(u1.z); s[7]=f2bf(u1.w);
            pb[h] = s;
        }
        __syncthreads();
        *reinterpret_cast<ushort8*>(&As[srow][scol])     = pa[0];
        *reinterpret_cast<ushort8*>(&As[srow][scol + 8]) = pa[1];
        *reinterpret_cast<ushort8*>(&Bs[srow][scol])     = pb[0];
        *reinterpret_cast<ushort8*>(&Bs[srow][scol + 8]) = pb[1];
        __syncthreads();

        short8 af[4], bf_[4];
#pragma unroll
        for (int i = 0; i < 4; ++i)
            af[i] = *reinterpret_cast<const short8*>(&As[wm + i * 16 + lmod][lk8]);
#pragma unroll
        for (int i = 0; i < 4; ++i)
            bf_[i] = *reinterpret_cast<const short8*>(&Bs[wn + i * 16 + lmod][lk8]);
#pragma unroll
        for (int i = 0; i < 4; ++i)
#pragma unroll
            for (int j = 0; j < 4; ++j)
                acc[i][j] = __builtin_amdgcn_mfma_f32_16x16x32_bf16(
                                af[i], bf_[j], acc[i][j], 0, 0, 0);
    }

#pragma unroll
    for (int j = 0; j < 4; ++j) {
        int n = nt * 128 + wn + j * 16 + lmod;
        float bb = bx[n] + bh[n];
#pragma unroll
        for (int i = 0; i < 4; ++i) {
            int mbase = mt * 128 + wm + i * 16 + (lane >> 4) * 4;
#pragma unroll
            for (int r = 0; r < 4; ++r)
                gx[(size_t)(mbase + r) * GDIM + n] = acc[i][j][r] + bb;
        }
    }
}

// ---------------------------------------------------------------------------
// Kernel 2: persistent LSTM recurrence.
// 64 blocks x 256 threads. Block b owns hidden units [b*16, b*16+16) = 64
// gate-cols. Wave (rh,kh) computes rows rh*32..+32 x all 64 cols over K-half
// kh*512..+512: all four waves read DISJOINT h chunks (128 KB/block/step,
// zero duplication). W_h K-half quadrant in registers (256 VGPR). Partials
// combined through gs[2]. 24-deep bypass-load pipeline. Per-wave flag poll.
// ---------------------------------------------------------------------------
__global__ __launch_bounds__(256, 1) void k_lstm(
        const float* __restrict__ gx, const float* __restrict__ Wh,
        const float* __restrict__ cinit, float* __restrict__ out,
        unsigned short* __restrict__ hbuf, unsigned* __restrict__ bar) {
    __shared__ __align__(16) float gs[2][64][68];         // 35 KB
    __shared__ __align__(16) unsigned short hs[64][16];   // 2 KB

    const int b    = blockIdx.x;     // 64
    const int tid  = threadIdx.x;    // 256
    const int lane = tid & 63;
    const int w    = tid >> 6;       // 0..3
    const int rh   = w >> 1;         // batch-row half
    const int kh   = w & 1;          // K half
    const int l15  = lane & 15;
    const int lk8  = (lane >> 4) * 8;

    // ---- W_h (64 cols x K-half) -> registers. breg[cg*16+ks]:
    //      col = cg*16 + l15 (gate cg, unit l15), k = kh*512 + ks*32 + lk8
    short8 breg[64];
#pragma unroll
    for (int cg = 0; cg < 4; ++cg) {
        const float* wb = Wh + ((size_t)(cg * HDIM + b * UPB + l15)) * HDIM
                        + kh * 512 + lk8;
#pragma unroll
        for (int ks = 0; ks < 16; ++ks)
            breg[cg * 16 + ks] = pack8(wb + ks * 32);
    }

    // ---- per-thread gate ownership: unit u, batch rows mg*4..mg*4+3
    const int u   = tid & 15;
    const int mg  = tid >> 4;        // 0..15
    const int col = b * UPB + u;     // global hidden index

    float c_reg[4];
#pragma unroll
    for (int r = 0; r < 4; ++r)
        c_reg[r] = cinit[(size_t)(mg * 4 + r) * HDIM + col];

    // gx for t=0
    float gxv[4][4];
#pragma unroll
    for (int r = 0; r < 4; ++r)
#pragma unroll
        for (int g = 0; g < 4; ++g)
            gxv[r][g] = gx[(size_t)(mg * 4 + r) * GDIM + g * HDIM + col];

    __syncthreads();

    for (int t = 0; t < T_STEPS; ++t) {
        // ---- per-wave poll: all 64 flags >= t  (h(t) visible at MALL)
        while (true) {
            unsigned v = __hip_atomic_load(&bar[lane * 32], __ATOMIC_RELAXED,
                                           __HIP_MEMORY_SCOPE_AGENT);
            if (__all((int)(v >= (unsigned)t))) break;
            __builtin_amdgcn_s_sleep(1);
        }
        asm volatile("" ::: "memory");   // keep bypass loads below the poll

        // ---- A stream: wave reads chunks (rh*2+rp)*32 + kh*16 + ks,
        //      rp in {0,1}, ks in 0..15. Each chunk = contiguous 1KB.
        const unsigned short* hA2 = hbuf + (size_t)(t & 1) * (BATCH * HDIM)
                                  + ((size_t)rh * 64 + kh * 16) * 512 + lane * 8;
        short8 st[24];
#define SLOT(i) ((i) < 24 ? (i) : (i) - 24)
#define ISSK(ks) do { \
        st[SLOT((ks) * 2)]     = ldg16(hA2 + (ks) * 512);          \
        st[SLOT((ks) * 2 + 1)] = ldg16(hA2 + 16384 + (ks) * 512);  \
    } while (0)
#define CONS1(ks) do { \
        short8 a0 = st[SLOT((ks) * 2)], a1 = st[SLOT((ks) * 2 + 1)]; \
        accP0 = __builtin_amdgcn_mfma_f32_16x16x32_bf16(a0, breg[(ks)],      accP0, 0, 0, 0); \
        accP1 = __builtin_amdgcn_mfma_f32_16x16x32_bf16(a0, breg[16 + (ks)], accP1, 0, 0, 0); \
        accP2 = __builtin_amdgcn_mfma_f32_16x16x32_bf16(a0, breg[32 + (ks)], accP2, 0, 0, 0); \
        accP3 = __builtin_amdgcn_mfma_f32_16x16x32_bf16(a0, breg[48 + (ks)], accP3, 0, 0, 0); \
        accQ0 = __builtin_amdgcn_mfma_f32_16x16x32_bf16(a1, breg[(ks)],      accQ0, 0, 0, 0); \
        accQ1 = __builtin_amdgcn_mfma_f32_16x16x32_bf16(a1, breg[16 + (ks)], accQ1, 0, 0, 0); \
        accQ2 = __builtin_amdgcn_mfma_f32_16x16x32_bf16(a1, breg[32 + (ks)], accQ2, 0, 0, 0); \
        accQ3 = __builtin_amdgcn_mfma_f32_16x16x32_bf16(a1, breg[48 + (ks)], accQ3, 0, 0, 0); \
    } while (0)

        f32x4 accP0 = {}, accP1 = {}, accP2 = {}, accP3 = {};
        f32x4 accQ0 = {}, accQ1 = {}, accQ2 = {}, accQ3 = {};
        ISSK(0); ISSK(1); ISSK(2);  ISSK(3);  ISSK(4);  ISSK(5);
        ISSK(6); ISSK(7); ISSK(8);  ISSK(9);  ISSK(10); ISSK(11);   // 24 in flight
        VMW(16); CONS1(0);  CONS1(1);  CONS1(2);  CONS1(3);
        ISSK(12); ISSK(13); ISSK(14); ISSK(15);
        VMW(16); CONS1(4);  CONS1(5);  CONS1(6);  CONS1(7);
        VMW(8);  CONS1(8);  CONS1(9);  CONS1(10); CONS1(11);
        VMW(0);  CONS1(12); CONS1(13); CONS1(14); CONS1(15);
#undef SLOT
#undef ISSK
#undef CONS1

        // ---- partials -> gs[kh]
        {
            const int gr = rh * 32 + (lane >> 4) * 4;
#pragma unroll
            for (int r = 0; r < 4; ++r) {
                gs[kh][gr + r][l15]           = accP0[r];
                gs[kh][gr + r][16 + l15]      = accP1[r];
                gs[kh][gr + r][32 + l15]      = accP2[r];
                gs[kh][gr + r][48 + l15]      = accP3[r];
                gs[kh][gr + 16 + r][l15]      = accQ0[r];
                gs[kh][gr + 16 + r][16 + l15] = accQ1[r];
                gs[kh][gr + 16 + r][32 + l15] = accQ2[r];
                gs[kh][gr + 16 + r][48 + l15] = accQ3[r];
            }
        }
        __syncthreads();

        // ---- gates + state update (all 256 threads, 4 batch rows each)
        float hv[4];
#pragma unroll
        for (int r = 0; r < 4; ++r) {
            const int m = mg * 4 + r;
            float xi = gxv[r][0] + gs[0][m][u]      + gs[1][m][u];
            float xf = gxv[r][1] + gs[0][m][16 + u] + gs[1][m][16 + u];
            float xo = gxv[r][2] + gs[0][m][32 + u] + gs[1][m][32 + u];
            float xn = gxv[r][3] + gs[0][m][48 + u] + gs[1][m][48 + u];
            float ig = fsigmoid(xi);
            float fg = fsigmoid(xf);
            float og = fsigmoid(xo);
            float ng = ftanh(xn);
            c_reg[r] = fg * c_reg[r] + ig * ng;
            float h = og * ftanh(c_reg[r]);
            hv[r] = h;
            hs[m][u] = f2bf(h);
        }

        if (t == T_STEPS - 1) {
            size_t fin = (size_t)T_STEPS * BATCH * HDIM;
#pragma unroll
            for (int r = 0; r < 4; ++r) {
                const int m = mg * 4 + r;
                out[((size_t)t * BATCH + m) * HDIM + col] = hv[r];
                out[fin + (size_t)m * HDIM + col] = hv[r];                           // h_fin
                out[fin + (size_t)BATCH * HDIM + (size_t)m * HDIM + col] = c_reg[r]; // c_fin
            }
            break;
        }

        __syncthreads();   // hs complete

        // ---- packed swizzled h store -> MALL (128 threads x 16B)
        if (tid < 128) {
            const int m  = tid >> 1;
            const int hh = tid & 1;
            ushort8 v = *reinterpret_cast<const ushort8*>(&hs[m][hh * 8]);
            size_t dst16 = ((size_t)(m >> 4) * 32 + (b >> 1)) * 64 + (m & 15)
                         + 16 * (((b & 1) << 1) | hh);
            stg16(hbuf + (size_t)((t + 1) & 1) * (BATCH * HDIM) + dst16 * 8, v);
        }
        VMW(0);            // asm stores drained to the coherence point
        __syncthreads();
        if (tid == 0)
            __hip_atomic_store(&bar[b * 32], (unsigned)(t + 1),
                               __ATOMIC_RELAXED, __HIP_MEMORY_SCOPE_AGENT);

        // ---- out stores for step t + gx prefetch (hidden under next poll)
#pragma unroll
        for (int r = 0; r < 4; ++r)
            out[((size_t)t * BATCH + mg * 4 + r) * HDIM + col] = hv[r];
        {
            const float* gp = gx + (size_t)(t + 1) * BATCH * GDIM;
#pragma unroll
            for (int r = 0; r < 4; ++r)
#pragma unroll
                for (int g = 0; g < 4; ++g)
                    gxv[r][g] = gp[(size_t)(mg * 4 + r) * GDIM + g * HDIM + col];
        }
    }
}

// ---------------------------------------------------------------------------
extern "C" void kernel_launch(void* const* d_in, const int* in_sizes, int n_in,
                              void* d_out, int out_size, void* d_ws, size_t ws_size,
                              hipStream_t stream) {
    const float* X  = (const float*)d_in[0];
    const float* h0 = (const float*)d_in[1];
    const float* c0 = (const float*)d_in[2];
    const float* Wx = (const float*)d_in[3];
    const float* Wh = (const float*)d_in[4];
    const float* bx = (const float*)d_in[5];
    const float* bh = (const float*)d_in[6];
    float* out = (float*)d_out;

    char* ws = (char*)d_ws;
    float* gx = (float*)ws;                                   // 512 MB fp32
    size_t gx_bytes = (size_t)T_STEPS * BATCH * GDIM * 4;
    unsigned short* hbuf = (unsigned short*)(ws + gx_bytes);  // 2 x 128 KB swizzled bf16
    size_t hbuf_bytes = (size_t)2 * BATCH * HDIM * 2;
    unsigned* bar = (unsigned*)(ws + gx_bytes + hbuf_bytes);  // 64 flags, 128B apart

    hipMemsetAsync(bar, 0, LSTM_BLOCKS * 32 * sizeof(unsigned), stream);
    k_h0_swz<<<dim3(32), dim3(256), 0, stream>>>(h0, hbuf);
    k_gx_gemm<<<dim3(8192), dim3(256), 0, stream>>>(X, Wx, bx, bh, gx);
    k_lstm<<<dim3(LSTM_BLOCKS), dim3(256), 0, stream>>>(gx, Wh, c0, out, hbuf, bar);
}

// Round 7
// 2803.411 us; speedup vs baseline: 5.8715x; 1.0925x over previous
//
#include <hip/hip_runtime.h>
#include <hip/hip_bf16.h>

// Problem constants
#define T_STEPS 512
#define BATCH   64
#define IDIM    1024
#define HDIM    1024
#define GDIM    4096   // 4*HDIM
#define UPB     16     // hidden units per recurrence block
#define LSTM_BLOCKS 64 // HDIM / UPB

typedef __attribute__((ext_vector_type(8))) short short8;
typedef __attribute__((ext_vector_type(8))) unsigned short ushort8;
typedef __attribute__((ext_vector_type(4))) float f32x4;

static __device__ __forceinline__ unsigned short f2bf(float f) {
    union { float f; unsigned u; } x; x.f = f;
    unsigned r = x.u + 0x7fffu + ((x.u >> 16) & 1u);  // round-to-nearest-even
    return (unsigned short)(r >> 16);
}

static __device__ __forceinline__ short8 pack8(const float* p) {
    float4 v0 = *reinterpret_cast<const float4*>(p);
    float4 v1 = *reinterpret_cast<const float4*>(p + 4);
    short8 t;
    t[0]=(short)f2bf(v0.x); t[1]=(short)f2bf(v0.y);
    t[2]=(short)f2bf(v0.z); t[3]=(short)f2bf(v0.w);
    t[4]=(short)f2bf(v1.x); t[5]=(short)f2bf(v1.y);
    t[6]=(short)f2bf(v1.z); t[7]=(short)f2bf(v1.w);
    return t;
}

// 16B coherent-bypass load/store (skip L1/L2; MALL coherence point).
static __device__ __forceinline__ short8 ldg16(const unsigned short* p) {
    short8 d;
    asm volatile("global_load_dwordx4 %0, %1, off sc0 sc1" : "=v"(d) : "v"(p));
    return d;
}
static __device__ __forceinline__ void stg16(unsigned short* p, ushort8 v) {
    asm volatile("global_store_dwordx4 %0, %1, off sc0 sc1"
                 :: "v"(p), "v"(v) : "memory");
}

// counted vmcnt wait + scheduler fence (keeps MFMAs from hoisting above it)
#define VMW(n) do { asm volatile("s_waitcnt vmcnt(" #n ")"); \
                    __builtin_amdgcn_sched_barrier(0); } while (0)

// fast activations: v_exp_f32 computes 2^x; v_rcp_f32 ~1ULP
static __device__ __forceinline__ float fexp2(float x) {
    float r; asm("v_exp_f32 %0, %1" : "=v"(r) : "v"(x)); return r;
}
static __device__ __forceinline__ float frcp(float x) {
    float r; asm("v_rcp_f32 %0, %1" : "=v"(r) : "v"(x)); return r;
}
static __device__ __forceinline__ float fsigmoid(float x) {
    return frcp(1.f + fexp2(-1.4426950408889634f * x));
}
static __device__ __forceinline__ float ftanh(float x) {
    return 2.f * frcp(1.f + fexp2(-2.8853900817779268f * x)) - 1.f;
}

// ---------------------------------------------------------------------------
// Kernel 0: h0 (fp32 [B,H]) -> swizzled bf16 buffer 0.
// 16B chunk index (Rtile*32 + s)*64 + lane holds
//   h[Rtile*16 + (lane&15)][s*32 + (lane>>4)*8 .. +8)
// ---------------------------------------------------------------------------
__global__ void k_h0_swz(const float* __restrict__ h0,
                         unsigned short* __restrict__ hbuf0) {
    int i = blockIdx.x * 256 + threadIdx.x;   // 8192 threads: 64 rows x 128 chunks
    int m  = i >> 7;
    int hh = i & 127;                         // u = hh*8
    const float* src = h0 + (size_t)m * HDIM + hh * 8;
    float4 a = *reinterpret_cast<const float4*>(src);
    float4 c = *reinterpret_cast<const float4*>(src + 4);
    ushort8 v;
    v[0]=f2bf(a.x); v[1]=f2bf(a.y); v[2]=f2bf(a.z); v[3]=f2bf(a.w);
    v[4]=f2bf(c.x); v[5]=f2bf(c.y); v[6]=f2bf(c.z); v[7]=f2bf(c.w);
    size_t dst16 = ((size_t)(m >> 4) * 32 + (hh >> 2)) * 64 + (m & 15) + 16 * (hh & 3);
    *reinterpret_cast<ushort8*>(hbuf0 + dst16 * 8) = v;  // kernel-end flush -> MALL
}

// ---------------------------------------------------------------------------
// Kernel 1: gx = input @ W_x^T + b_x + b_h   (unchanged; passed rounds 1-6)
// ---------------------------------------------------------------------------
__global__ __launch_bounds__(256) void k_gx_gemm(
        const float* __restrict__ X, const float* __restrict__ Wx,
        const float* __restrict__ bx, const float* __restrict__ bh,
        float* __restrict__ gx) {
    __shared__ unsigned short As[128][40];
    __shared__ unsigned short Bs[128][40];

    const int bid  = blockIdx.x;
    const int nt   = bid & 31;     // 32 N tiles
    const int mt   = bid >> 5;     // 256 M tiles
    const int tid  = threadIdx.x;
    const int lane = tid & 63;
    const int w    = tid >> 6;
    const int wm   = (w >> 1) * 64;
    const int wn   = (w & 1) * 64;
    const int lmod = lane & 15;
    const int lk8  = (lane >> 4) * 8;

    f32x4 acc[4][4] = {};

    const int srow = tid >> 1;
    const int scol = (tid & 1) * 16;
    const float* Abase = X  + (size_t)(mt * 128 + srow) * 1024 + scol;
    const float* Bbase = Wx + (size_t)(nt * 128 + srow) * 1024 + scol;

    for (int k0 = 0; k0 < 1024; k0 += 32) {
        const float4* a4 = reinterpret_cast<const float4*>(Abase + k0);
        const float4* b4 = reinterpret_cast<const float4*>(Bbase + k0);
        ushort8 pa[2], pb[2];
#pragma unroll
        for (int h = 0; h < 2; ++h) {
            float4 v0 = a4[h * 2], v1 = a4[h * 2 + 1];
            ushort8 t;
            t[0]=f2bf(v0.x); t[1]=f2bf(v0.y); t[2]=f2bf(v0.z); t[3]=f2bf(v0.w);
            t[4]=f2bf(v1.x); t[5]=f2bf(v1.y); t[6]=f2bf(v1.z); t[7]=f2bf(v1.w);
            pa[h] = t;
            float4 u0 = b4[h * 2], u1 = b4[h * 2 + 1];
            ushort8 s;
            s[0]=f2bf(u0.x); s[1]=f2bf(u0.y); s[2]=f2bf(u0.z); s[3]=f2bf(u0.w);
            s[4]=f2bf(u1.x); s[5]=f2bf(u1.y); s[6]=f2bf(u1.z); s[7]=f2bf(u1.w);
            pb[h] = s;
        }
        __syncthreads();
        *reinterpret_cast<ushort8*>(&As[srow][scol])     = pa[0];
        *reinterpret_cast<ushort8*>(&As[srow][scol + 8]) = pa[1];
        *reinterpret_cast<ushort8*>(&Bs[srow][scol])     = pb[0];
        *reinterpret_cast<ushort8*>(&Bs[srow][scol + 8]) = pb[1];
        __syncthreads();

        short8 af[4], bf_[4];
#pragma unroll
        for (int i = 0; i < 4; ++i)
            af[i] = *reinterpret_cast<const short8*>(&As[wm + i * 16 + lmod][lk8]);
#pragma unroll
        for (int i = 0; i < 4; ++i)
            bf_[i] = *reinterpret_cast<const short8*>(&Bs[wn + i * 16 + lmod][lk8]);
#pragma unroll
        for (int i = 0; i < 4; ++i)
#pragma unroll
            for (int j = 0; j < 4; ++j)
                acc[i][j] = __builtin_amdgcn_mfma_f32_16x16x32_bf16(
                                af[i], bf_[j], acc[i][j], 0, 0, 0);
    }

#pragma unroll
    for (int j = 0; j < 4; ++j) {
        int n = nt * 128 + wn + j * 16 + lmod;
        float bb = bx[n] + bh[n];
#pragma unroll
        for (int i = 0; i < 4; ++i) {
            int mbase = mt * 128 + wm + i * 16 + (lane >> 4) * 4;
#pragma unroll
            for (int r = 0; r < 4; ++r)
                gx[(size_t)(mbase + r) * GDIM + n] = acc[i][j][r] + bb;
        }
    }
}

// ---------------------------------------------------------------------------
// Kernel 2: persistent LSTM recurrence.
// 64 blocks x 256 threads. Block b owns hidden units [b*16, b*16+16) = 64
// gate-cols. Wave (rh,kh): rows rh*32..+32 x 64 cols x K-half kh*512..+512;
// disjoint A chunks. W_h K-half in registers. Chain-tightened: poll runs with
// ZERO outstanding vmem (gx/out drained pre-poll) and each wave polls only
// its 32 producer flags (write-safety: both halves join at the gs sync
// before any h(t+1) store).
// ---------------------------------------------------------------------------
__global__ __launch_bounds__(256, 1) void k_lstm(
        const float* __restrict__ gx, const float* __restrict__ Wh,
        const float* __restrict__ cinit, float* __restrict__ out,
        unsigned short* __restrict__ hbuf, unsigned* __restrict__ bar) {
    __shared__ __align__(16) float gs[2][64][68];         // 35 KB
    __shared__ __align__(16) unsigned short hs[64][16];   // 2 KB

    const int b    = blockIdx.x;     // 64
    const int tid  = threadIdx.x;    // 256
    const int lane = tid & 63;
    const int w    = tid >> 6;       // 0..3
    const int rh   = w >> 1;         // batch-row half
    const int kh   = w & 1;          // K half
    const int l15  = lane & 15;
    const int lk8  = (lane >> 4) * 8;

    // ---- W_h (64 cols x K-half) -> registers. breg[cg*16+ks]:
    //      col = cg*16 + l15 (gate cg, unit l15), k = kh*512 + ks*32 + lk8
    short8 breg[64];
#pragma unroll
    for (int cg = 0; cg < 4; ++cg) {
        const float* wb = Wh + ((size_t)(cg * HDIM + b * UPB + l15)) * HDIM
                        + kh * 512 + lk8;
#pragma unroll
        for (int ks = 0; ks < 16; ++ks)
            breg[cg * 16 + ks] = pack8(wb + ks * 32);
    }

    // ---- per-thread gate ownership: unit u, batch rows mg*4..mg*4+3
    const int u   = tid & 15;
    const int mg  = tid >> 4;        // 0..15
    const int col = b * UPB + u;     // global hidden index

    float c_reg[4];
#pragma unroll
    for (int r = 0; r < 4; ++r)
        c_reg[r] = cinit[(size_t)(mg * 4 + r) * HDIM + col];

    // gx for t=0
    float gxv[4][4];
#pragma unroll
    for (int r = 0; r < 4; ++r)
#pragma unroll
        for (int g = 0; g < 4; ++g)
            gxv[r][g] = gx[(size_t)(mg * 4 + r) * GDIM + g * HDIM + col];

    __syncthreads();   // also drains the gxv/c_reg loads: t=0 poll is clean

    // this wave's flag subset: producers [kh*32, kh*32+32), 32 lines
    const unsigned* fb = &bar[(kh * 32 + (lane & 31)) * 32];

    for (int t = 0; t < T_STEPS; ++t) {
        // ---- poll (clean: no outstanding vmem when we get here)
        {
            unsigned v = __hip_atomic_load(fb, __ATOMIC_RELAXED,
                                           __HIP_MEMORY_SCOPE_AGENT);
            while (!__all((int)(v >= (unsigned)t))) {
                __builtin_amdgcn_s_sleep(2);
                v = __hip_atomic_load(fb, __ATOMIC_RELAXED,
                                      __HIP_MEMORY_SCOPE_AGENT);
            }
        }
        asm volatile("" ::: "memory");   // keep bypass loads below the poll

        // ---- A stream: chunks (rh*2+rp)*32 + kh*16 + ks, contiguous 1KB each
        const unsigned short* hA2 = hbuf + (size_t)(t & 1) * (BATCH * HDIM)
                                  + ((size_t)rh * 64 + kh * 16) * 512 + lane * 8;
        short8 st[24];
#define SLOT(i) ((i) < 24 ? (i) : (i) - 24)
#define ISSK(ks) do { \
        st[SLOT((ks) * 2)]     = ldg16(hA2 + (ks) * 512);          \
        st[SLOT((ks) * 2 + 1)] = ldg16(hA2 + 16384 + (ks) * 512);  \
    } while (0)
#define CONS1(ks) do { \
        short8 a0 = st[SLOT((ks) * 2)], a1 = st[SLOT((ks) * 2 + 1)]; \
        accP0 = __builtin_amdgcn_mfma_f32_16x16x32_bf16(a0, breg[(ks)],      accP0, 0, 0, 0); \
        accP1 = __builtin_amdgcn_mfma_f32_16x16x32_bf16(a0, breg[16 + (ks)], accP1, 0, 0, 0); \
        accP2 = __builtin_amdgcn_mfma_f32_16x16x32_bf16(a0, breg[32 + (ks)], accP2, 0, 0, 0); \
        accP3 = __builtin_amdgcn_mfma_f32_16x16x32_bf16(a0, breg[48 + (ks)], accP3, 0, 0, 0); \
        accQ0 = __builtin_amdgcn_mfma_f32_16x16x32_bf16(a1, breg[(ks)],      accQ0, 0, 0, 0); \
        accQ1 = __builtin_amdgcn_mfma_f32_16x16x32_bf16(a1, breg[16 + (ks)], accQ1, 0, 0, 0); \
        accQ2 = __builtin_amdgcn_mfma_f32_16x16x32_bf16(a1, breg[32 + (ks)], accQ2, 0, 0, 0); \
        accQ3 = __builtin_amdgcn_mfma_f32_16x16x32_bf16(a1, breg[48 + (ks)], accQ3, 0, 0, 0); \
    } while (0)

        f32x4 accP0 = {}, accP1 = {}, accP2 = {}, accP3 = {};
        f32x4 accQ0 = {}, accQ1 = {}, accQ2 = {}, accQ3 = {};
        ISSK(0); ISSK(1); ISSK(2);  ISSK(3);  ISSK(4);  ISSK(5);
        ISSK(6); ISSK(7); ISSK(8);  ISSK(9);  ISSK(10); ISSK(11);   // 24 in flight
        VMW(16); CONS1(0);  CONS1(1);  CONS1(2);  CONS1(3);
        ISSK(12); ISSK(13); ISSK(14); ISSK(15);
        VMW(16); CONS1(4);  CONS1(5);  CONS1(6);  CONS1(7);
        VMW(8);  CONS1(8);  CONS1(9);  CONS1(10); CONS1(11);
        VMW(0);  CONS1(12); CONS1(13); CONS1(14); CONS1(15);
#undef SLOT
#undef ISSK
#undef CONS1

        // ---- partials -> gs[kh]
        {
            const int gr = rh * 32 + (lane >> 4) * 4;
#pragma unroll
            for (int r = 0; r < 4; ++r) {
                gs[kh][gr + r][l15]           = accP0[r];
                gs[kh][gr + r][16 + l15]      = accP1[r];
                gs[kh][gr + r][32 + l15]      = accP2[r];
                gs[kh][gr + r][48 + l15]      = accP3[r];
                gs[kh][gr + 16 + r][l15]      = accQ0[r];
                gs[kh][gr + 16 + r][16 + l15] = accQ1[r];
                gs[kh][gr + 16 + r][32 + l15] = accQ2[r];
                gs[kh][gr + 16 + r][48 + l15] = accQ3[r];
            }
        }
        __syncthreads();   // joins both kh halves: all 64 flags verified >= t

        // ---- gates + state update (all 256 threads, 4 batch rows each)
        float hv[4];
#pragma unroll
        for (int r = 0; r < 4; ++r) {
            const int m = mg * 4 + r;
            float xi = gxv[r][0] + gs[0][m][u]      + gs[1][m][u];
            float xf = gxv[r][1] + gs[0][m][16 + u] + gs[1][m][16 + u];
            float xo = gxv[r][2] + gs[0][m][32 + u] + gs[1][m][32 + u];
            float xn = gxv[r][3] + gs[0][m][48 + u] + gs[1][m][48 + u];
            float ig = fsigmoid(xi);
            float fg = fsigmoid(xf);
            float og = fsigmoid(xo);
            float ng = ftanh(xn);
            c_reg[r] = fg * c_reg[r] + ig * ng;
            float h = og * ftanh(c_reg[r]);
            hv[r] = h;
            hs[m][u] = f2bf(h);
        }

        if (t == T_STEPS - 1) {
            size_t fin = (size_t)T_STEPS * BATCH * HDIM;
#pragma unroll
            for (int r = 0; r < 4; ++r) {
                const int m = mg * 4 + r;
                out[((size_t)t * BATCH + m) * HDIM + col] = hv[r];
                out[fin + (size_t)m * HDIM + col] = hv[r];                           // h_fin
                out[fin + (size_t)BATCH * HDIM + (size_t)m * HDIM + col] = c_reg[r]; // c_fin
            }
            break;
        }

        __syncthreads();   // hs complete

        // ---- packed swizzled h store -> MALL (128 threads x 16B)
        if (tid < 128) {
            const int m  = tid >> 1;
            const int hh = tid & 1;
            ushort8 v = *reinterpret_cast<const ushort8*>(&hs[m][hh * 8]);
            size_t dst16 = ((size_t)(m >> 4) * 32 + (b >> 1)) * 64 + (m & 15)
                         + 16 * (((b & 1) << 1) | hh);
            stg16(hbuf + (size_t)((t + 1) & 1) * (BATCH * HDIM) + dst16 * 8, v);
        }
        // __syncthreads implies per-wave s_waitcnt vmcnt(0): h stores of ALL
        // storing waves are at the coherence point before the flag goes up.
        __syncthreads();
        if (tid == 0)
            __hip_atomic_store(&bar[b * 32], (unsigned)(t + 1),
                               __ATOMIC_RELAXED, __HIP_MEMORY_SCOPE_AGENT);

        // ---- out stores + gx prefetch, then FULL drain so the next poll
        //      loop has zero outstanding vmem (drain hides under producers)
#pragma unroll
        for (int r = 0; r < 4; ++r)
            out[((size_t)t * BATCH + mg * 4 + r) * HDIM + col] = hv[r];
        {
            const float* gp = gx + (size_t)(t + 1) * BATCH * GDIM;
#pragma unroll
            for (int r = 0; r < 4; ++r)
#pragma unroll
                for (int g = 0; g < 4; ++g)
                    gxv[r][g] = gp[(size_t)(mg * 4 + r) * GDIM + g * HDIM + col];
        }
        VMW(0);
    }
}

// ---------------------------------------------------------------------------
extern "C" void kernel_launch(void* const* d_in, const int* in_sizes, int n_in,
                              void* d_out, int out_size, void* d_ws, size_t ws_size,
                              hipStream_t stream) {
    const float* X  = (const float*)d_in[0];
    const float* h0 = (const float*)d_in[1];
    const float* c0 = (const float*)d_in[2];
    const float* Wx = (const float*)d_in[3];
    const float* Wh = (const float*)d_in[4];
    const float* bx = (const float*)d_in[5];
    const float* bh = (const float*)d_in[6];
    float* out = (float*)d_out;

    char* ws = (char*)d_ws;
    float* gx = (float*)ws;                                   // 512 MB fp32
    size_t gx_bytes = (size_t)T_STEPS * BATCH * GDIM * 4;
    unsigned short* hbuf = (unsigned short*)(ws + gx_bytes);  // 2 x 128 KB swizzled bf16
    size_t hbuf_bytes = (size_t)2 * BATCH * HDIM * 2;
    unsigned* bar = (unsigned*)(ws + gx_bytes + hbuf_bytes);  // 64 flags, 128B apart

    hipMemsetAsync(bar, 0, LSTM_BLOCKS * 32 * sizeof(unsigned), stream);
    k_h0_swz<<<dim3(32), dim3(256), 0, stream>>>(h0, hbuf);
    k_gx_gemm<<<dim3(8192), dim3(256), 0, stream>>>(X, Wx, bx, bh, gx);
    k_lstm<<<dim3(LSTM_BLOCKS), dim3(256), 0, stream>>>(gx, Wh, c0, out, hbuf, bar);
}